// Round 5
// baseline (44.297 us; speedup 1.0000x reference)
//
#include <hip/hip_runtime.h>
#include <cstddef>

// Problem constants (match reference)
constexpr int H_ = 320;
constexpr int W_ = 320;
constexpr int HW_ = H_ * W_;            // 102400
constexpr int NK = 440;                 // offsets excluding center
constexpr int SR = 16;                  // strip rows (full-width strips)
constexpr int NSTRIP = H_ / SR;         // 20
constexpr int KC = 11;                  // k-offsets per chunk
constexpr int NKC = NK / KC;            // 40
constexpr int SMOOTH_BLOCKS = NSTRIP * NKC;   // 800
constexpr int NPART = SMOOTH_BLOCKS + NSTRIP; // 820
constexpr int HALO = 10;
constexpr int LROWS = SR + 2 * HALO;    // 36
constexpr int LCOLS = W_ + 2 * HALO;    // 340
constexpr int LSTRIDE = LCOLS + 1;      // 341 (odd -> worst LDS aliasing small)
constexpr int NQ = SR * W_ / (256 * 4); // 5 float4-quads per thread per plane

typedef float f32x4 __attribute__((ext_vector_type(4)));

__device__ __forceinline__ int clampi(int v, int lo, int hi) {
    return v < lo ? lo : (v > hi ? hi : v);
}

// full-block reduce; rbuf is 4 floats of shared mem. Safe to call twice
// (leading barrier protects rbuf reuse). Result valid on all threads.
__device__ __forceinline__ float block_reduce(float v, float* rbuf, int tid) {
    __syncthreads();
    for (int off = 32; off > 0; off >>= 1)
        v += __shfl_down(v, off, 64);
    if ((tid & 63) == 0) rbuf[tid >> 6] = v;
    __syncthreads();
    return rbuf[0] + rbuf[1] + rbuf[2] + rbuf[3];
}

__global__ __launch_bounds__(256) void bsl_main_kernel(
    const float* __restrict__ img,   // [H,W]
    const float* __restrict__ tgt,   // [H,W]
    const float* __restrict__ w,     // [440,H,W]
    float* __restrict__ partials)    // [NPART]
{
    __shared__ float lds[LROWS * LSTRIDE];   // 36*341*4 = 49,104 B -> 3 blocks/CU
    __shared__ float rbuf[4];
    const int tid = threadIdx.x;

    const int strip = blockIdx.x / NKC;      // 0..19
    const int kc    = blockIdx.x % NKC;      // 0..39
    const int y0 = strip * SR;

    // ---- stage img strip + halo into LDS (replicate padding via clamp) ----
    for (int e = tid; e < LROWS * LCOLS; e += 256) {
        const int ly = e / LCOLS, lx = e - ly * LCOLS;
        const int gy = clampi(y0 - HALO + ly, 0, H_ - 1);
        const int gx = clampi(lx - HALO, 0, W_ - 1);
        lds[ly * LSTRIDE + lx] = img[gy * W_ + gx];
    }
    __syncthreads();

    // per-quad LDS center addresses + center values (quads never cross rows:
    // p multiple of 4, W multiple of 4)
    int   cbase[NQ];
    float c[NQ][4];
#pragma unroll
    for (int i = 0; i < NQ; ++i) {
        const int p  = i * 1024 + tid * 4;   // 0..5116
        const int r  = p / W_;               // 0..15
        const int cc = p - r * W_;
        cbase[i] = (HALO + r) * LSTRIDE + HALO + cc;
        c[i][0] = lds[cbase[i] + 0];
        c[i][1] = lds[cbase[i] + 1];
        c[i][2] = lds[cbase[i] + 2];
        c[i][3] = lds[cbase[i] + 3];
    }

    // ---- stream KC w-plane strips; each wave load = 1 KB contiguous ----
    float sacc = 0.f;
    const float* wp = w + (size_t)(kc * KC) * HW_ + y0 * W_ + tid * 4;
#pragma unroll 1
    for (int kk = 0; kk < KC; ++kk) {
        const int bk  = kc * KC + kk;                // w-plane index (center skipped)
        const int idx = (bk < 220) ? bk : bk + 1;    // re-insert center gap
        const int q   = idx / 21;
        const int soff = (q - 10) * LSTRIDE + (idx - q * 21 - 10); // wave-uniform

        f32x4 wv[NQ];
#pragma unroll
        for (int i = 0; i < NQ; ++i)
            wv[i] = __builtin_nontemporal_load((const f32x4*)(wp + i * 1024));

#pragma unroll
        for (int i = 0; i < NQ; ++i) {
            const int nb = cbase[i] + soff;
            const float n0 = lds[nb + 0];
            const float n1 = lds[nb + 1];
            const float n2 = lds[nb + 2];
            const float n3 = lds[nb + 3];
            const float d0 = c[i][0] - n0, d1 = c[i][1] - n1;
            const float d2 = c[i][2] - n2, d3 = c[i][3] - n3;
            sacc += wv[i].x * d0 * d0;
            sacc += wv[i].y * d1 * d1;
            sacc += wv[i].z * d2 * d2;
            sacc += wv[i].w * d3 * d3;
        }
        wp += HW_;
    }

    const float ssum = block_reduce(sacc, rbuf, tid);
    if (tid == 0) partials[blockIdx.x] = ssum;

    // ---- data term: once per strip (kc==0 blocks) ----
    if (kc == 0) {
        float dacc = 0.f;
        const float* tp = tgt + y0 * W_ + tid * 4;
#pragma unroll
        for (int i = 0; i < NQ; ++i) {
            const float4 t4 = *reinterpret_cast<const float4*>(tp + i * 1024);
            const float d0 = c[i][0] - t4.x, d1 = c[i][1] - t4.y;
            const float d2 = c[i][2] - t4.z, d3 = c[i][3] - t4.w;
            dacc += d0 * d0 + d1 * d1 + d2 * d2 + d3 * d3;
        }
        const float dsum = block_reduce(dacc, rbuf, tid);
        if (tid == 0) partials[SMOOTH_BLOCKS + strip] = dsum;
    }
}

__global__ __launch_bounds__(256) void bsl_final_kernel(
    const float* __restrict__ partials, float* __restrict__ out)
{
    const int tid = threadIdx.x;
    double s = 0.0, d = 0.0;
    for (int i = tid; i < SMOOTH_BLOCKS; i += 256) s += (double)partials[i];
    if (tid < NSTRIP) d = (double)partials[SMOOTH_BLOCKS + tid];

    __shared__ double sm[256];
    __shared__ double sd[256];
    sm[tid] = s; sd[tid] = d;
    __syncthreads();
    for (int st = 128; st > 0; st >>= 1) {
        if (tid < st) { sm[tid] += sm[tid + st]; sd[tid] += sd[tid + st]; }
        __syncthreads();
    }
    if (tid == 0) {
        // H*W*LAM*mean(w d^2) = LAM * S / 440 ; data = D / (H*W)
        out[0] = (float)(128.0 * sm[0] / 440.0 + sd[0] / (double)HW_);
    }
}

extern "C" void kernel_launch(void* const* d_in, const int* in_sizes, int n_in,
                              void* d_out, int out_size, void* d_ws, size_t ws_size,
                              hipStream_t stream) {
    const float* img = (const float*)d_in[0];   // output [320,320]
    const float* tgt = (const float*)d_in[1];   // target [320,320]
    const float* wij = (const float*)d_in[2];   // w_ij [440,320,320]
    float* out = (float*)d_out;
    float* partials = (float*)d_ws;             // NPART floats = 3.3 KB

    bsl_main_kernel<<<SMOOTH_BLOCKS, 256, 0, stream>>>(img, tgt, wij, partials);
    bsl_final_kernel<<<1, 256, 0, stream>>>(partials, out);
}

// Round 6
// 38.425 us; speedup vs baseline: 1.1528x; 1.1528x over previous
//
#include <hip/hip_runtime.h>
#include <cstddef>

// Problem constants (match reference)
constexpr int H_ = 320;
constexpr int W_ = 320;
constexpr int HW_ = H_ * W_;            // 102400
constexpr int NK = 440;                 // offsets excluding center
constexpr int TR = 8;                   // tile rows (full-width tiles)
constexpr int NTILES = H_ / TR;         // 40
constexpr int KC = 10;                  // k-offsets per chunk
constexpr int NKC = NK / KC;            // 44
constexpr int SMOOTH_BLOCKS = NTILES * NKC;   // 1760
constexpr int NPART = SMOOTH_BLOCKS + NTILES; // 1800
constexpr int HALO = 10;
constexpr int LROWS = TR + 2 * HALO;    // 28
constexpr int LCOLS = W_ + 2 * HALO;    // 340
constexpr int LSTRIDE = LCOLS + 1;      // 341 (odd)
constexpr int NT_ = 320;                // threads (5 waves); 320*8 px = tile

typedef float f32x4 __attribute__((ext_vector_type(4)));

__device__ __forceinline__ int clampi(int v, int lo, int hi) {
    return v < lo ? lo : (v > hi ? hi : v);
}

// full-block reduce over 5 waves; result valid on all threads.
__device__ __forceinline__ float block_reduce(float v, float* rbuf, int tid) {
    __syncthreads();
    for (int off = 32; off > 0; off >>= 1)
        v += __shfl_down(v, off, 64);
    if ((tid & 63) == 0) rbuf[tid >> 6] = v;
    __syncthreads();
    return rbuf[0] + rbuf[1] + rbuf[2] + rbuf[3] + rbuf[4];
}

__global__ __launch_bounds__(NT_, 5) void bsl_main_kernel(
    const float* __restrict__ img,   // [H,W]
    const float* __restrict__ tgt,   // [H,W]
    const float* __restrict__ w,     // [440,H,W]
    float* __restrict__ partials)    // [NPART]
{
    __shared__ float lds[LROWS * LSTRIDE];   // 28*341*4 = 38,192 B -> 4 blocks/CU
    __shared__ float rbuf[5];
    const int tid = threadIdx.x;

    const int tileId = blockIdx.x / NKC;     // 0..39
    const int kc     = blockIdx.x % NKC;     // 0..43
    const int y0 = tileId * TR;

    // ---- stage img tile + halo into LDS (replicate padding via clamp) ----
    for (int e = tid; e < LROWS * LCOLS; e += NT_) {
        const int ly = e / LCOLS, lx = e - ly * LCOLS;
        const int gy = clampi(y0 - HALO + ly, 0, H_ - 1);
        const int gx = clampi(lx - HALO, 0, W_ - 1);
        lds[ly * LSTRIDE + lx] = img[gy * W_ + gx];
    }
    __syncthreads();

    // thread t -> 2 quads of the 8x320 tile: px0 = 4t, px1 = 1280 + 4t
    const int px0 = 4 * tid;                 // 0..1276
    const int r0  = px0 / W_;                // 0..3
    const int cc  = px0 - r0 * W_;
    const int cb0 = (HALO + r0) * LSTRIDE + HALO + cc;
    const int cb1 = cb0 + 4 * LSTRIDE;       // +4 rows
    float ca[4], cb[4];
#pragma unroll
    for (int j = 0; j < 4; ++j) { ca[j] = lds[cb0 + j]; cb[j] = lds[cb1 + j]; }

    // ---- stream KC plane-tiles; each plane-tile = 10 KB contiguous ----
    float sacc = 0.f;
    const float* wq = w + (size_t)(kc * KC) * HW_ + y0 * W_ + px0;
    for (int kk = 0; kk < KC; kk += 2) {
        // two planes' offsets (wave-uniform scalars)
        const int bka  = kc * KC + kk;
        const int idxa = (bka < 220) ? bka : bka + 1;
        const int qa   = idxa / 21;
        const int sofa = (qa - 10) * LSTRIDE + (idxa - qa * 21 - 10);
        const int bkb  = bka + 1;
        const int idxb = (bkb < 220) ? bkb : bkb + 1;
        const int qb   = idxb / 21;
        const int sofb = (qb - 10) * LSTRIDE + (idxb - qb * 21 - 10);

        // issue all 4 loads before any consumption
        const f32x4 wa0 = __builtin_nontemporal_load((const f32x4*)(wq));
        const f32x4 wa1 = __builtin_nontemporal_load((const f32x4*)(wq + 1280));
        const f32x4 wb0 = __builtin_nontemporal_load((const f32x4*)(wq + HW_));
        const f32x4 wb1 = __builtin_nontemporal_load((const f32x4*)(wq + HW_ + 1280));
        wq += 2 * HW_;

        // plane A
        {
            const int n0 = cb0 + sofa, n1 = cb1 + sofa;
            const float d0 = ca[0] - lds[n0 + 0], d1 = ca[1] - lds[n0 + 1];
            const float d2 = ca[2] - lds[n0 + 2], d3 = ca[3] - lds[n0 + 3];
            const float e0 = cb[0] - lds[n1 + 0], e1 = cb[1] - lds[n1 + 1];
            const float e2 = cb[2] - lds[n1 + 2], e3 = cb[3] - lds[n1 + 3];
            sacc += wa0.x * d0 * d0 + wa0.y * d1 * d1
                  + wa0.z * d2 * d2 + wa0.w * d3 * d3;
            sacc += wa1.x * e0 * e0 + wa1.y * e1 * e1
                  + wa1.z * e2 * e2 + wa1.w * e3 * e3;
        }
        // plane B
        {
            const int n0 = cb0 + sofb, n1 = cb1 + sofb;
            const float d0 = ca[0] - lds[n0 + 0], d1 = ca[1] - lds[n0 + 1];
            const float d2 = ca[2] - lds[n0 + 2], d3 = ca[3] - lds[n0 + 3];
            const float e0 = cb[0] - lds[n1 + 0], e1 = cb[1] - lds[n1 + 1];
            const float e2 = cb[2] - lds[n1 + 2], e3 = cb[3] - lds[n1 + 3];
            sacc += wb0.x * d0 * d0 + wb0.y * d1 * d1
                  + wb0.z * d2 * d2 + wb0.w * d3 * d3;
            sacc += wb1.x * e0 * e0 + wb1.y * e1 * e1
                  + wb1.z * e2 * e2 + wb1.w * e3 * e3;
        }
    }

    const float ssum = block_reduce(sacc, rbuf, tid);
    if (tid == 0) partials[blockIdx.x] = ssum;

    // ---- data term: once per tile (kc==0 blocks) ----
    if (kc == 0) {
        const float4 t0 = *reinterpret_cast<const float4*>(tgt + y0 * W_ + px0);
        const float4 t1 = *reinterpret_cast<const float4*>(tgt + y0 * W_ + 1280 + px0);
        const float d0 = ca[0] - t0.x, d1 = ca[1] - t0.y;
        const float d2 = ca[2] - t0.z, d3 = ca[3] - t0.w;
        const float e0 = cb[0] - t1.x, e1 = cb[1] - t1.y;
        const float e2 = cb[2] - t1.z, e3 = cb[3] - t1.w;
        const float dsum = block_reduce(d0*d0 + d1*d1 + d2*d2 + d3*d3
                                      + e0*e0 + e1*e1 + e2*e2 + e3*e3, rbuf, tid);
        if (tid == 0) partials[SMOOTH_BLOCKS + tileId] = dsum;
    }
}

__global__ __launch_bounds__(256) void bsl_final_kernel(
    const float* __restrict__ partials, float* __restrict__ out)
{
    const int tid = threadIdx.x;
    double s = 0.0, d = 0.0;

    // smooth partials: 1760 floats = 1024 + 736, both multiples of 4
    for (int base = 0; base < SMOOTH_BLOCKS; base += 1024) {
        const int i = base + tid * 4;
        if (i + 4 <= SMOOTH_BLOCKS) {
            const float4 v = *reinterpret_cast<const float4*>(partials + i);
            s += (double)v.x + (double)v.y + (double)v.z + (double)v.w;
        }
    }
    // data partials: 40 floats
    if (tid < NTILES / 4) {
        const float4 v = *reinterpret_cast<const float4*>(
            partials + SMOOTH_BLOCKS + tid * 4);
        d += (double)v.x + (double)v.y + (double)v.z + (double)v.w;
    }

    __shared__ double sm[256];
    __shared__ double sd[256];
    sm[tid] = s; sd[tid] = d;
    __syncthreads();
    for (int st = 128; st > 0; st >>= 1) {
        if (tid < st) { sm[tid] += sm[tid + st]; sd[tid] += sd[tid + st]; }
        __syncthreads();
    }
    if (tid == 0) {
        // H*W*LAM*mean(w d^2) = LAM * S / 440 ; data = D / (H*W)
        out[0] = (float)(128.0 * sm[0] / 440.0 + sd[0] / (double)HW_);
    }
}

extern "C" void kernel_launch(void* const* d_in, const int* in_sizes, int n_in,
                              void* d_out, int out_size, void* d_ws, size_t ws_size,
                              hipStream_t stream) {
    const float* img = (const float*)d_in[0];   // output [320,320]
    const float* tgt = (const float*)d_in[1];   // target [320,320]
    const float* wij = (const float*)d_in[2];   // w_ij [440,320,320]
    float* out = (float*)d_out;
    float* partials = (float*)d_ws;             // NPART floats = 7.2 KB

    bsl_main_kernel<<<SMOOTH_BLOCKS, NT_, 0, stream>>>(img, tgt, wij, partials);
    bsl_final_kernel<<<1, 256, 0, stream>>>(partials, out);
}